// Round 1
// baseline (6087.189 us; speedup 1.0000x reference)
//
#include <hip/hip_runtime.h>

// ConvLSTM2D: B=8, T=16, H=W=64, Cin=32, F=64, 3x3 'SAME' convs,
// gates [i,f,c,o], act=relu, rec_act=hard_sigmoid, returns final h.
//
// Strategy (round 1, fp32 baseline):
//  - 16 sequential step-kernels (recurrence over T).
//  - Per step: fused conv(x_t,W)+conv(h,U)+b + gate math + c/h update.
//  - Grid: 8x8 spatial tiles x 8 batch = 512 blocks, 256 threads.
//  - LDS: x halo tile (10x10x32) + h halo tile (10x10x64) = 38.4 KB.
//  - Thread: 2x2 pixels x 16 z-channels = 64 fp32 accumulators.
//  - Gate combine via __shfl within wave (i,f,c,o slices are lanes
//    cg, cg+4, cg+8, cg+12 of the same wave).
//  - h ping-pong: d_out doubles as the odd-step buffer so t=15 writes d_out.
//  - t=0: h=c=0 handled by has_prev flag (skip h-conv and c read).

#define H_DIM 64
#define W_DIM 64
#define CIN   32
#define FCH   64
#define ZCH   256
#define TSTEPS 16

__device__ __forceinline__ float hsig(float x) {
    // jax.nn.hard_sigmoid = relu6(x+3)/6
    return fminf(fmaxf((x + 3.0f) * (1.0f / 6.0f), 0.0f), 1.0f);
}

__global__ __launch_bounds__(256)
void convlstm_step(const float* __restrict__ x,    // (B,T,H,W,CIN)
                   const float* __restrict__ Wg,   // (3,3,CIN,256)
                   const float* __restrict__ Ug,   // (3,3,FCH,256)
                   const float* __restrict__ bias, // (256)
                   const float* __restrict__ h_in, // (B,H,W,FCH) or null
                   float* __restrict__ c_st,       // (B,H,W,FCH) in/out
                   float* __restrict__ h_out,      // (B,H,W,FCH)
                   int t, int has_prev)
{
    __shared__ float xs[10 * 10 * CIN];   // 12.8 KB
    __shared__ float hsl[10 * 10 * FCH];  // 25.6 KB

    const int tid = threadIdx.x;
    const int gx0 = blockIdx.x * 8;
    const int gy0 = blockIdx.y * 8;
    const int b   = blockIdx.z;

    const float* xt = x + (((size_t)b * TSTEPS + t) * (size_t)(H_DIM * W_DIM * CIN));

    // ---- stage x halo tile: 100 pixels x 8 float4 ----
    for (int idx = tid; idx < 100 * 8; idx += 256) {
        int pix = idx >> 3, q = idx & 7;
        int iy = pix / 10, ix = pix - iy * 10;
        int gy = gy0 + iy - 1, gx = gx0 + ix - 1;
        float4 v = make_float4(0.f, 0.f, 0.f, 0.f);
        if ((unsigned)gy < 64u && (unsigned)gx < 64u)
            v = *(const float4*)(xt + ((size_t)(gy * 64 + gx) * CIN) + q * 4);
        *(float4*)(xs + pix * CIN + q * 4) = v;
    }
    // ---- stage h halo tile: 100 pixels x 16 float4 ----
    if (has_prev) {
        const float* hb = h_in + ((size_t)b * (H_DIM * W_DIM * FCH));
        for (int idx = tid; idx < 100 * 16; idx += 256) {
            int pix = idx >> 4, q = idx & 15;
            int iy = pix / 10, ix = pix - iy * 10;
            int gy = gy0 + iy - 1, gx = gx0 + ix - 1;
            float4 v = make_float4(0.f, 0.f, 0.f, 0.f);
            if ((unsigned)gy < 64u && (unsigned)gx < 64u)
                v = *(const float4*)(hb + ((size_t)(gy * 64 + gx) * FCH) + q * 4);
            *(float4*)(hsl + pix * FCH + q * 4) = v;
        }
    }
    __syncthreads();

    // thread -> (pixel-group, channel-group)
    const int pg = tid >> 4;           // 16 groups of 2x2 pixels
    const int cg = tid & 15;           // 16 groups of 16 z-channels
    const int py0 = (pg >> 2) * 2;
    const int px0 = (pg & 3) * 2;

    float acc[4][16];
    {
        const float4* bp = (const float4*)(bias + cg * 16);
        float4 b0 = bp[0], b1 = bp[1], b2 = bp[2], b3 = bp[3];
        float bl[16] = {b0.x, b0.y, b0.z, b0.w, b1.x, b1.y, b1.z, b1.w,
                        b2.x, b2.y, b2.z, b2.w, b3.x, b3.y, b3.z, b3.w};
        #pragma unroll
        for (int p = 0; p < 4; ++p)
            #pragma unroll
            for (int c = 0; c < 16; ++c) acc[p][c] = bl[c];
    }

    // ---- conv(x_t, W) ----
    #pragma unroll
    for (int dy = 0; dy < 3; ++dy)
    #pragma unroll
    for (int dx = 0; dx < 3; ++dx) {
        const float* wt  = Wg + (size_t)((dy * 3 + dx) * CIN) * ZCH + cg * 16;
        const float* xsb = xs + ((py0 + dy) * 10 + (px0 + dx)) * CIN;
        #pragma unroll 4
        for (int k = 0; k < CIN; ++k) {
            const float* wr = wt + (size_t)k * ZCH;
            float4 w0 = *(const float4*)(wr);
            float4 w1 = *(const float4*)(wr + 4);
            float4 w2 = *(const float4*)(wr + 8);
            float4 w3 = *(const float4*)(wr + 12);
            float a00 = xsb[k];
            float a01 = xsb[CIN + k];
            float a10 = xsb[10 * CIN + k];
            float a11 = xsb[11 * CIN + k];
            float wv[16] = {w0.x, w0.y, w0.z, w0.w, w1.x, w1.y, w1.z, w1.w,
                            w2.x, w2.y, w2.z, w2.w, w3.x, w3.y, w3.z, w3.w};
            #pragma unroll
            for (int c = 0; c < 16; ++c) {
                acc[0][c] = fmaf(a00, wv[c], acc[0][c]);
                acc[1][c] = fmaf(a01, wv[c], acc[1][c]);
                acc[2][c] = fmaf(a10, wv[c], acc[2][c]);
                acc[3][c] = fmaf(a11, wv[c], acc[3][c]);
            }
        }
    }

    // ---- conv(h, U) ----
    if (has_prev) {
        #pragma unroll
        for (int dy = 0; dy < 3; ++dy)
        #pragma unroll
        for (int dx = 0; dx < 3; ++dx) {
            const float* wt  = Ug + (size_t)((dy * 3 + dx) * FCH) * ZCH + cg * 16;
            const float* hsb = hsl + ((py0 + dy) * 10 + (px0 + dx)) * FCH;
            #pragma unroll 4
            for (int k = 0; k < FCH; ++k) {
                const float* wr = wt + (size_t)k * ZCH;
                float4 w0 = *(const float4*)(wr);
                float4 w1 = *(const float4*)(wr + 4);
                float4 w2 = *(const float4*)(wr + 8);
                float4 w3 = *(const float4*)(wr + 12);
                float a00 = hsb[k];
                float a01 = hsb[FCH + k];
                float a10 = hsb[10 * FCH + k];
                float a11 = hsb[11 * FCH + k];
                float wv[16] = {w0.x, w0.y, w0.z, w0.w, w1.x, w1.y, w1.z, w1.w,
                                w2.x, w2.y, w2.z, w2.w, w3.x, w3.y, w3.z, w3.w};
                #pragma unroll
                for (int c = 0; c < 16; ++c) {
                    acc[0][c] = fmaf(a00, wv[c], acc[0][c]);
                    acc[1][c] = fmaf(a01, wv[c], acc[1][c]);
                    acc[2][c] = fmaf(a10, wv[c], acc[2][c]);
                    acc[3][c] = fmaf(a11, wv[c], acc[3][c]);
                }
            }
        }
    }

    // ---- gate combine (i,f,c,o live on lanes cg, cg+4, cg+8, cg+12) ----
    const int lane = tid & 63;
    #pragma unroll
    for (int p = 0; p < 4; ++p) {
        float zf_[16], zc_[16], zo_[16];
        #pragma unroll
        for (int c = 0; c < 16; ++c) {
            zf_[c] = __shfl(acc[p][c], lane + 4, 64);
            zc_[c] = __shfl(acc[p][c], lane + 8, 64);
            zo_[c] = __shfl(acc[p][c], lane + 12, 64);
        }
        if (cg < 4) {  // these threads own output channels [cg*16, cg*16+16)
            int gy = gy0 + py0 + (p >> 1);
            int gx = gx0 + px0 + (p & 1);
            size_t base = (((size_t)b * 64 + gy) * 64 + gx) * FCH + cg * 16;
            float cv[16];
            if (has_prev) {
                const float4* cp = (const float4*)(c_st + base);
                float4 c0 = cp[0], c1 = cp[1], c2 = cp[2], c3 = cp[3];
                float tmp[16] = {c0.x, c0.y, c0.z, c0.w, c1.x, c1.y, c1.z, c1.w,
                                 c2.x, c2.y, c2.z, c2.w, c3.x, c3.y, c3.z, c3.w};
                #pragma unroll
                for (int c = 0; c < 16; ++c) cv[c] = tmp[c];
            } else {
                #pragma unroll
                for (int c = 0; c < 16; ++c) cv[c] = 0.f;
            }
            float cn[16], hn[16];
            #pragma unroll
            for (int c = 0; c < 16; ++c) {
                float ig = hsig(acc[p][c]);
                float fg = hsig(zf_[c]);
                float og = hsig(zo_[c]);
                float cand = fmaxf(zc_[c], 0.f);
                cn[c] = fg * cv[c] + ig * cand;
                hn[c] = og * fmaxf(cn[c], 0.f);
            }
            float4* cpo = (float4*)(c_st + base);
            float4* hpo = (float4*)(h_out + base);
            cpo[0] = make_float4(cn[0], cn[1], cn[2], cn[3]);
            cpo[1] = make_float4(cn[4], cn[5], cn[6], cn[7]);
            cpo[2] = make_float4(cn[8], cn[9], cn[10], cn[11]);
            cpo[3] = make_float4(cn[12], cn[13], cn[14], cn[15]);
            hpo[0] = make_float4(hn[0], hn[1], hn[2], hn[3]);
            hpo[1] = make_float4(hn[4], hn[5], hn[6], hn[7]);
            hpo[2] = make_float4(hn[8], hn[9], hn[10], hn[11]);
            hpo[3] = make_float4(hn[12], hn[13], hn[14], hn[15]);
        }
    }
}

extern "C" void kernel_launch(void* const* d_in, const int* in_sizes, int n_in,
                              void* d_out, int out_size, void* d_ws, size_t ws_size,
                              hipStream_t stream) {
    const float* x  = (const float*)d_in[0];
    const float* Wg = (const float*)d_in[1];
    const float* Ug = (const float*)d_in[2];
    const float* bs = (const float*)d_in[3];

    const size_t HSZ = (size_t)8 * 64 * 64 * 64;  // 2,097,152 floats
    float* hA = (float*)d_out;               // odd-step output; final (t=15) lands here
    float* hB = (float*)d_ws;                // even-step output
    float* cS = (float*)d_ws + HSZ;          // cell state (in-place)

    dim3 grid(8, 8, 8);   // (W/8, H/8, B)
    dim3 block(256);
    for (int t = 0; t < TSTEPS; ++t) {
        const float* hin = (t == 0) ? nullptr : ((t & 1) ? hB : hA);
        float* hout = (t & 1) ? hA : hB;
        convlstm_step<<<grid, block, 0, stream>>>(x, Wg, Ug, bs, hin, cS, hout,
                                                  t, (t > 0) ? 1 : 0);
    }
}

// Round 2
// 486.582 us; speedup vs baseline: 12.5101x; 12.5101x over previous
//
#include <hip/hip_runtime.h>

// ConvLSTM2D via MFMA implicit-GEMM. B=8,T=16,H=W=64,Cin=32,F=64,3x3 SAME.
// z[p, 0:256] = sum_k A[p,k] * Bw[k,0:256], K = 9*32 (x) + 9*64 (h) = 864.
//
// Per step-kernel block: 8x8 pixel tile x 256 z-channels, 4 waves.
// Wave w owns N-tiles {w, w+4, w+8, w+12} -> gates i/f/c/o for channel
// w*16+col are in the same lane/reg across the 4 tile-groups (no shuffle).
// A (x-halo 10x10x32 + h-halo 10x10x64) staged once to LDS as bf16 with
// padded pixel strides (40 / 72 elems) -> <=2-way bank aliasing (free).
// K-loop is barrier-free: ds_read_b128 A + L2-hit prepacked B + MFMA.
//
// Weights prepacked each launch to B-frag order: [s(27)][nt(16)][lane(64)][8].
// h ping-pongs as bf16 in ws; c-state lives fp32 in d_out (t=15 epilogue
// replaces it with h fp32, same-lane read-then-write).

#define TSTEPS 16

typedef short bf16x8 __attribute__((ext_vector_type(8)));
typedef float f32x4 __attribute__((ext_vector_type(4)));

__device__ __forceinline__ float hsig(float x) {
    return fminf(fmaxf((x + 3.0f) * (1.0f / 6.0f), 0.0f), 1.0f);
}

__device__ __forceinline__ unsigned short f2bf(float f) {
    union { float f; unsigned int u; } v; v.f = f;
    unsigned int r = v.u + 0x7fffu + ((v.u >> 16) & 1u);  // RNE
    return (unsigned short)(r >> 16);
}

// ---- weight prepack: Wg(3,3,32,256), Ug(3,3,64,256) fp32 -> bf16 B-frags ----
// out[s][nt][lane][j]: B[k=(lane>>4)*8+j][n=nt*16+(lane&15)] for k-step s.
__global__ __launch_bounds__(256)
void prepack_w(const float* __restrict__ Wg, const float* __restrict__ Ug,
               unsigned short* __restrict__ out)
{
    int idx = blockIdx.x * 256 + threadIdx.x;   // 27*16*64 = 27648
    if (idx >= 27648) return;
    int lane = idx & 63;
    int nt   = (idx >> 6) & 15;
    int s    = idx >> 10;
    int col = lane & 15, quad = lane >> 4;
    int n = nt * 16 + col;
    int k0 = quad * 8;
    const float* src;
    if (s < 9) {
        src = Wg + ((size_t)s * 32 + k0) * 256 + n;
    } else {
        int ss = s - 9; int tap = ss >> 1; int half = ss & 1;
        src = Ug + ((size_t)tap * 64 + half * 32 + k0) * 256 + n;
    }
    unsigned short tmp[8];
    #pragma unroll
    for (int j = 0; j < 8; ++j) tmp[j] = f2bf(src[(size_t)j * 256]);
    *(uint4*)(out + (size_t)idx * 8) = *(uint4*)tmp;
}

// ---- one ConvLSTM step ----
__global__ __launch_bounds__(256)
void convlstm_step(const float* __restrict__ x,       // (B,T,64,64,32) fp32
                   const unsigned short* __restrict__ wpk, // packed B-frags
                   const float* __restrict__ bias,    // (256)
                   const unsigned short* __restrict__ h_in, // bf16 (B,64,64,64)
                   float* __restrict__ c_st,          // fp32 (B,64,64,64) = d_out
                   unsigned short* __restrict__ h_out,// bf16 ping
                   int t, int has_prev, int is_last)
{
    __shared__ __align__(16) unsigned short xs_s[100 * 40]; // 8.0 KB (pad 32->40)
    __shared__ __align__(16) unsigned short hs_s[100 * 72]; // 14.4 KB (pad 64->72)

    const int tid = threadIdx.x;
    const int gx0 = blockIdx.x * 8;
    const int gy0 = blockIdx.y * 8;
    const int b   = blockIdx.z;

    // ---- stage x halo (fp32 -> bf16) ----
    {
        const float* xt = x + (((size_t)b * TSTEPS + t) * (size_t)(64 * 64 * 32));
        for (int idx = tid; idx < 100 * 8; idx += 256) {
            int pix = idx >> 3, q = idx & 7;
            int iy = pix / 10, ix = pix - iy * 10;
            int gy = gy0 + iy - 1, gx = gx0 + ix - 1;
            unsigned short o[4] = {0, 0, 0, 0};
            if ((unsigned)gy < 64u && (unsigned)gx < 64u) {
                float4 v = *(const float4*)(xt + ((size_t)(gy * 64 + gx) * 32) + q * 4);
                o[0] = f2bf(v.x); o[1] = f2bf(v.y); o[2] = f2bf(v.z); o[3] = f2bf(v.w);
            }
            *(ushort4*)(xs_s + pix * 40 + q * 4) = *(ushort4*)o;
        }
    }
    // ---- stage h halo (bf16 copy) ----
    if (has_prev) {
        const unsigned short* hb = h_in + ((size_t)b * (64 * 64 * 64));
        for (int idx = tid; idx < 100 * 8; idx += 256) {
            int pix = idx >> 3, q = idx & 7;          // q: 8 bf16 chunk
            int iy = pix / 10, ix = pix - iy * 10;
            int gy = gy0 + iy - 1, gx = gx0 + ix - 1;
            uint4 v = make_uint4(0u, 0u, 0u, 0u);
            if ((unsigned)gy < 64u && (unsigned)gx < 64u)
                v = *(const uint4*)(hb + ((size_t)(gy * 64 + gx) * 64) + q * 8);
            *(uint4*)(hs_s + pix * 72 + q * 8) = v;
        }
    }
    __syncthreads();

    const int lane = tid & 63;
    const int w    = tid >> 6;      // wave id 0..3
    const int quad = lane >> 4;
    const int m    = lane & 15;

    // A-frag base addresses (element offsets) per M-tile
    int xbase[4], hbase[4];
    #pragma unroll
    for (int mt = 0; mt < 4; ++mt) {
        int p = mt * 16 + m;
        int py = p >> 3, px = p & 7;
        xbase[mt] = (py * 10 + px) * 40 + quad * 8;
        hbase[mt] = (py * 10 + px) * 72 + quad * 8;
    }

    f32x4 acc[4][4];   // [mt][gate]
    #pragma unroll
    for (int mt = 0; mt < 4; ++mt)
        #pragma unroll
        for (int g = 0; g < 4; ++g)
            acc[mt][g] = (f32x4){0.f, 0.f, 0.f, 0.f};

    // ---- x-conv: 9 k-steps (one 3x3 tap each, K=32=Cin) ----
    #pragma unroll
    for (int s = 0; s < 9; ++s) {
        const int taplin = (s / 3) * 10 + (s % 3);
        bf16x8 a[4];
        #pragma unroll
        for (int mt = 0; mt < 4; ++mt)
            a[mt] = *(const bf16x8*)(xs_s + xbase[mt] + taplin * 40);
        #pragma unroll
        for (int g = 0; g < 4; ++g) {
            bf16x8 bf = *(const bf16x8*)(wpk + ((size_t)((s * 16 + (w + 4 * g)) * 64 + lane)) * 8);
            #pragma unroll
            for (int mt = 0; mt < 4; ++mt)
                acc[mt][g] = __builtin_amdgcn_mfma_f32_16x16x32_bf16(a[mt], bf, acc[mt][g], 0, 0, 0);
        }
    }
    // ---- h-conv: 18 k-steps (tap x half, K=32 each) ----
    if (has_prev) {
        #pragma unroll
        for (int s = 0; s < 18; ++s) {
            const int tap = s >> 1, half = s & 1;
            const int taplin = (tap / 3) * 10 + (tap % 3);
            bf16x8 a[4];
            #pragma unroll
            for (int mt = 0; mt < 4; ++mt)
                a[mt] = *(const bf16x8*)(hs_s + hbase[mt] + taplin * 72 + half * 32);
            #pragma unroll
            for (int g = 0; g < 4; ++g) {
                bf16x8 bf = *(const bf16x8*)(wpk + ((size_t)(((9 + s) * 16 + (w + 4 * g)) * 64 + lane)) * 8);
                #pragma unroll
                for (int mt = 0; mt < 4; ++mt)
                    acc[mt][g] = __builtin_amdgcn_mfma_f32_16x16x32_bf16(a[mt], bf, acc[mt][g], 0, 0, 0);
            }
        }
    }

    // ---- epilogue: gates + state update ----
    // C/D layout: col = lane&15 (z-channel within tile), row = quad*4 + r (pixel)
    const int col = lane & 15;
    const int ch  = w * 16 + col;               // output channel 0..63
    const float b_i = bias[ch];
    const float b_f = bias[64 + ch];
    const float b_c = bias[128 + ch];
    const float b_o = bias[192 + ch];

    #pragma unroll
    for (int mt = 0; mt < 4; ++mt) {
        #pragma unroll
        for (int r = 0; r < 4; ++r) {
            int p = mt * 16 + quad * 4 + r;
            int py = p >> 3, px = p & 7;
            size_t gidx = (((size_t)b * 64 + (gy0 + py)) * 64 + (gx0 + px)) * 64 + ch;
            float zi = acc[mt][0][r] + b_i;
            float zf = acc[mt][1][r] + b_f;
            float zc = acc[mt][2][r] + b_c;
            float zo = acc[mt][3][r] + b_o;
            float c_prev = has_prev ? c_st[gidx] : 0.0f;
            float cn = hsig(zf) * c_prev + hsig(zi) * fmaxf(zc, 0.0f);
            float hn = hsig(zo) * fmaxf(cn, 0.0f);
            if (is_last) {
                c_st[gidx] = hn;            // d_out gets final h (fp32)
            } else {
                c_st[gidx] = cn;
                h_out[gidx] = f2bf(hn);
            }
        }
    }
}

extern "C" void kernel_launch(void* const* d_in, const int* in_sizes, int n_in,
                              void* d_out, int out_size, void* d_ws, size_t ws_size,
                              hipStream_t stream) {
    const float* x  = (const float*)d_in[0];
    const float* Wg = (const float*)d_in[1];
    const float* Ug = (const float*)d_in[2];
    const float* bs = (const float*)d_in[3];

    // ws layout: [packed weights 442368 B][h0 bf16 4 MB][h1 bf16 4 MB]
    unsigned short* wpk = (unsigned short*)d_ws;
    unsigned short* h0  = (unsigned short*)((char*)d_ws + 27 * 16 * 64 * 8 * 2);
    unsigned short* h1  = h0 + (size_t)8 * 64 * 64 * 64;
    float* cS = (float*)d_out;   // c-state lives in d_out; t=15 overwrites with h

    prepack_w<<<108, 256, 0, stream>>>(Wg, Ug, wpk);

    dim3 grid(8, 8, 8);
    dim3 block(256);
    for (int t = 0; t < TSTEPS; ++t) {
        const unsigned short* hin = (t == 0) ? nullptr : ((t & 1) ? h0 : h1);
        unsigned short* hout = (t & 1) ? h1 : h0;
        convlstm_step<<<grid, block, 0, stream>>>(x, wpk, bs, hin, cS, hout,
                                                  t, (t > 0) ? 1 : 0,
                                                  (t == TSTEPS - 1) ? 1 : 0);
    }
}